// Round 1
// baseline (63.706 us; speedup 1.0000x reference)
//
#include <hip/hip_runtime.h>
#include <math.h>

#define T 34
#define V 14
#define NT 256

__global__ __launch_bounds__(NT) void micro_fwd(
    const int* __restrict__ idx,
    const float* __restrict__ p_tokA, const float* __restrict__ p_tokStart,
    const float* __restrict__ p_tokStride, const float* __restrict__ p_spAmp,
    const float* __restrict__ p_spPhase, const float* __restrict__ p_spSlope,
    const float* __restrict__ p_spOffset, const float* __restrict__ norm_w,
    const float* __restrict__ q_w, const float* __restrict__ q_phase,
    const float* __restrict__ out_A, const float* __restrict__ out_B,
    const float* __restrict__ fc1_w, const float* __restrict__ fc2_w,
    const float* __restrict__ head_w, float* __restrict__ out)
{
    __shared__ float TE[V][2];       // token arc embedding table
    __shared__ float POS[T][3];      // spiral positional embedding
    __shared__ float KS[T][5];       // k = pos @ q_w^T
    __shared__ float QS[T][5];       // q = rotated k
    __shared__ float ATT[T][T];      // softmaxed causal attention (lower-tri valid)
    __shared__ float G[V][T];        // g(v,t) = rmsnorm(x(v,t)) . out_A
    __shared__ float gbuf[NT][T];    // per-thread g[s] for its row
    __shared__ unsigned char tokbuf[NT * T]; // per-thread token ids (VOCAB=14 fits u8)

    const int tid = threadIdx.x;

    const float tokA = p_tokA[0], tokStart = p_tokStart[0], tokStride = p_tokStride[0];
    const float spAmp = p_spAmp[0], spPhase = p_spPhase[0];
    const float spSlope = p_spSlope[0], spOffset = p_spOffset[0];

    // ---- Phase A: tok_emb + pos tables ----
    if (tid < V) {
        float ang = tokStart + (float)tid * tokStride;
        TE[tid][0] = tokA * cosf(ang);
        TE[tid][1] = tokA * sinf(ang);
    }
    if (tid < T) {
        float th = (float)tid * 0.62831853071795864769f + spPhase; // 2*pi/10
        POS[tid][0] = spAmp * cosf(th);
        POS[tid][1] = spAmp * sinf(th);
        POS[tid][2] = spSlope * (float)tid + spOffset;
    }
    __syncthreads();

    // ---- Phase B: q/k + G table ----
    if (tid < T) {
        float p0 = POS[tid][0], p1 = POS[tid][1], p2 = POS[tid][2];
        float kk[5];
        #pragma unroll
        for (int i = 0; i < 5; ++i)
            kk[i] = p0 * q_w[3 * i] + p1 * q_w[3 * i + 1] + p2 * q_w[3 * i + 2];
        float c = cosf(q_phase[0]), s = sinf(q_phase[0]);
        #pragma unroll
        for (int i = 0; i < 5; ++i) KS[tid][i] = kk[i];
        QS[tid][0] = c * kk[0] - s * kk[1];
        QS[tid][1] = s * kk[0] + c * kk[1];
        QS[tid][2] = kk[2]; QS[tid][3] = kk[3]; QS[tid][4] = kk[4];
    }
    for (int e = tid; e < V * T; e += NT) {
        int v = e / T, t = e - v * T;
        float x0 = TE[v][0], x1 = TE[v][1];
        float x2 = POS[t][0], x3 = POS[t][1], x4 = POS[t][2];
        float ms = (x0*x0 + x1*x1 + x2*x2 + x3*x3 + x4*x4) * 0.2f;
        float r = rsqrtf(ms + 1e-5f);
        G[v][t] = (x0 * norm_w[0] * out_A[0] + x1 * norm_w[1] * out_A[1]
                 + x2 * norm_w[2] * out_A[2] + x3 * norm_w[3] * out_A[3]
                 + x4 * norm_w[4] * out_A[4]) * r;
    }
    __syncthreads();

    // ---- Phase C: attention rows (causal softmax), 3-pass to avoid scratch ----
    if (tid < T) {
        const int t = tid;
        float q0 = QS[t][0], q1 = QS[t][1], q2 = QS[t][2], q3 = QS[t][3], q4 = QS[t][4];
        float mx = -1e30f;
        for (int s2 = 0; s2 <= t; ++s2) {
            float d = (q0 * KS[s2][0] + q1 * KS[s2][1] + q2 * KS[s2][2]
                     + q3 * KS[s2][3] + q4 * KS[s2][4]) * 0.44721359549995793928f;
            ATT[t][s2] = d;
            mx = fmaxf(mx, d);
        }
        float sum = 0.f;
        for (int s2 = 0; s2 <= t; ++s2) {
            float e = expf(ATT[t][s2] - mx);
            ATT[t][s2] = e;
            sum += e;
        }
        float inv = 1.f / sum;
        for (int s2 = 0; s2 <= t; ++s2) ATT[t][s2] *= inv;
    }

    // ---- cooperative, coalesced idx staging ----
    {
        const int base = (int)blockIdx.x * (NT * T);
        for (int i = tid; i < NT * T; i += NT)
            tokbuf[i] = (unsigned char)idx[base + i];
    }
    __syncthreads();

    // ---- per-thread g[s] fill ----
    #pragma unroll
    for (int s2 = 0; s2 < T; ++s2) {
        int tok = tokbuf[tid * T + s2];
        gbuf[tid][s2] = G[tok][s2];
    }

    // ---- weights into registers (all static-indexed) ----
    float nw[5], oB[5], w1[2][5], w2b[5][2], hw[2][5], te0r[V], te1r[V];
    #pragma unroll
    for (int d = 0; d < 5; ++d) { nw[d] = norm_w[d]; oB[d] = out_B[d]; }
    #pragma unroll
    for (int j = 0; j < 2; ++j) {
        #pragma unroll
        for (int d = 0; d < 5; ++d) { w1[j][d] = fc1_w[j*5+d]; hw[j][d] = head_w[j*5+d]; }
    }
    #pragma unroll
    for (int d = 0; d < 5; ++d) { w2b[d][0] = fc2_w[2*d]; w2b[d][1] = fc2_w[2*d+1]; }
    #pragma unroll
    for (int v = 0; v < V; ++v) { te0r[v] = TE[v][0]; te1r[v] = TE[v][1]; }

    const int b = blockIdx.x * NT + tid;
    float* orow = out + (size_t)b * (T * V);

    // ---- main per-row loop ----
    for (int t = 0; t < T; ++t) {
        // attention scalar: attn row (broadcast) . per-thread g
        float acc = 0.f;
        for (int s2 = 0; s2 <= t; ++s2)
            acc = fmaf(ATT[t][s2], gbuf[tid][s2], acc);

        int tok = tokbuf[tid * T + t];
        float x0 = TE[tok][0] + acc * oB[0];
        float x1 = TE[tok][1] + acc * oB[1];
        float x2 = POS[t][0] + acc * oB[2];
        float x3 = POS[t][1] + acc * oB[3];
        float x4 = POS[t][2] + acc * oB[4];

        // FFN (pre-norm)
        float ms = (x0*x0 + x1*x1 + x2*x2 + x3*x3 + x4*x4) * 0.2f;
        float r = rsqrtf(ms + 1e-5f);
        float h0 = x0*r*nw[0], h1 = x1*r*nw[1], h2 = x2*r*nw[2], h3 = x3*r*nw[3], h4 = x4*r*nw[4];
        float f0 = fmaxf(0.f, h0*w1[0][0] + h1*w1[0][1] + h2*w1[0][2] + h3*w1[0][3] + h4*w1[0][4]);
        float f1 = fmaxf(0.f, h0*w1[1][0] + h1*w1[1][1] + h2*w1[1][2] + h3*w1[1][3] + h4*w1[1][4]);
        x0 += f0*w2b[0][0] + f1*w2b[0][1];
        x1 += f0*w2b[1][0] + f1*w2b[1][1];
        x2 += f0*w2b[2][0] + f1*w2b[2][1];
        x3 += f0*w2b[3][0] + f1*w2b[3][1];
        x4 += f0*w2b[4][0] + f1*w2b[4][1];

        // head (pre-norm)
        ms = (x0*x0 + x1*x1 + x2*x2 + x3*x3 + x4*x4) * 0.2f;
        r = rsqrtf(ms + 1e-5f);
        h0 = x0*r*nw[0]; h1 = x1*r*nw[1]; h2 = x2*r*nw[2]; h3 = x3*r*nw[3]; h4 = x4*r*nw[4];
        float p0 = h0*hw[0][0] + h1*hw[0][1] + h2*hw[0][2] + h3*hw[0][3] + h4*hw[0][4];
        float p1 = h0*hw[1][0] + h1*hw[1][1] + h2*hw[1][2] + h3*hw[1][3] + h4*hw[1][4];

        float o[V];
        #pragma unroll
        for (int v = 0; v < V; ++v)
            o[v] = p0 * te0r[v] + p1 * te1r[v];

        float2* op = reinterpret_cast<float2*>(orow + t * V);
        #pragma unroll
        for (int i = 0; i < 7; ++i)
            op[i] = make_float2(o[2*i], o[2*i+1]);
    }
}

extern "C" void kernel_launch(void* const* d_in, const int* in_sizes, int n_in,
                              void* d_out, int out_size, void* d_ws, size_t ws_size,
                              hipStream_t stream) {
    const int*   idx        = (const int*)  d_in[0];
    const float* tok_A      = (const float*)d_in[1];
    const float* tok_start  = (const float*)d_in[2];
    const float* tok_stride = (const float*)d_in[3];
    const float* sp_amp     = (const float*)d_in[4];
    const float* sp_phase   = (const float*)d_in[5];
    const float* sp_slope   = (const float*)d_in[6];
    const float* sp_offset  = (const float*)d_in[7];
    const float* norm_w     = (const float*)d_in[8];
    const float* q_w        = (const float*)d_in[9];
    const float* q_phase    = (const float*)d_in[10];
    const float* out_A      = (const float*)d_in[11];
    const float* out_B      = (const float*)d_in[12];
    const float* fc1_w      = (const float*)d_in[13];
    const float* fc2_w      = (const float*)d_in[14];
    const float* head_w     = (const float*)d_in[15];
    float* out = (float*)d_out;

    // 65536 rows, one thread per row: 256 blocks x 256 threads
    micro_fwd<<<256, NT, 0, stream>>>(idx, tok_A, tok_start, tok_stride,
                                      sp_amp, sp_phase, sp_slope, sp_offset,
                                      norm_w, q_w, q_phase, out_A, out_B,
                                      fc1_w, fc2_w, head_w, out);
}

// Round 2
// 47.898 us; speedup vs baseline: 1.3300x; 1.3300x over previous
//
#include <hip/hip_runtime.h>
#include <math.h>

#define T 34
#define V 14
#define NT 256
#define NBLK 2176          // 8.5 blocks/CU; 8704 groups / 2176 = 4 groups per block
#define NGROUPS 8704       // 65536*34 / 256 exactly
#define MAXROWS 9          // rows a 256-item group can span (ceil(256/34)+1)

__global__ __launch_bounds__(NT, 4) void micro_fwd(
    const int* __restrict__ idx,
    const float* __restrict__ p_tokA, const float* __restrict__ p_tokStart,
    const float* __restrict__ p_tokStride, const float* __restrict__ p_spAmp,
    const float* __restrict__ p_spPhase, const float* __restrict__ p_spSlope,
    const float* __restrict__ p_spOffset, const float* __restrict__ norm_w,
    const float* __restrict__ q_w, const float* __restrict__ q_phase,
    const float* __restrict__ out_A, const float* __restrict__ out_B,
    const float* __restrict__ fc1_w, const float* __restrict__ fc2_w,
    const float* __restrict__ head_w, float* __restrict__ out)
{
    __shared__ float TE[V][2];          // token arc embedding
    __shared__ float POS[T][3];         // spiral positional embedding
    __shared__ float KS[T][5];          // k
    __shared__ float QS[T][5];          // q (rotated k)
    __shared__ float ATTT[T][T];        // TRANSPOSED softmaxed attention: ATTT[s][t], zero-padded s>t
    __shared__ float G[V][T];           // g(v,t) = rmsnorm(x(v,t)) . out_A
    __shared__ float gb[MAXROWS][T];    // per-group per-row g values
    __shared__ unsigned char tokb[MAXROWS * T];
    __shared__ float4 stage4[NT * 14 / 4];  // 14336 B output staging

    const int tid = threadIdx.x;
    float* stagef = reinterpret_cast<float*>(stage4);

    const float tokA = p_tokA[0], tokStart = p_tokStart[0], tokStride = p_tokStride[0];
    const float spAmp = p_spAmp[0], spPhase = p_spPhase[0];
    const float spSlope = p_spSlope[0], spOffset = p_spOffset[0];

    // ================= per-block table setup =================
    if (tid < V) {
        float ang = tokStart + (float)tid * tokStride;
        TE[tid][0] = tokA * cosf(ang);
        TE[tid][1] = tokA * sinf(ang);
    }
    if (tid < T) {
        float th = (float)tid * 0.62831853071795864769f + spPhase; // 2*pi/10
        POS[tid][0] = spAmp * cosf(th);
        POS[tid][1] = spAmp * sinf(th);
        POS[tid][2] = spSlope * (float)tid + spOffset;
    }
    __syncthreads();

    if (tid < T) {
        float p0 = POS[tid][0], p1 = POS[tid][1], p2 = POS[tid][2];
        float kk[5];
        #pragma unroll
        for (int i = 0; i < 5; ++i)
            kk[i] = p0 * q_w[3 * i] + p1 * q_w[3 * i + 1] + p2 * q_w[3 * i + 2];
        float c = cosf(q_phase[0]), s = sinf(q_phase[0]);
        #pragma unroll
        for (int i = 0; i < 5; ++i) KS[tid][i] = kk[i];
        QS[tid][0] = c * kk[0] - s * kk[1];
        QS[tid][1] = s * kk[0] + c * kk[1];
        QS[tid][2] = kk[2]; QS[tid][3] = kk[3]; QS[tid][4] = kk[4];
    }
    for (int e = tid; e < V * T; e += NT) {
        int v = e / T, t = e - v * T;
        float x0 = TE[v][0], x1 = TE[v][1];
        float x2 = POS[t][0], x3 = POS[t][1], x4 = POS[t][2];
        float ms = (x0*x0 + x1*x1 + x2*x2 + x3*x3 + x4*x4) * 0.2f;
        float r = rsqrtf(ms + 1e-5f);
        G[v][t] = (x0 * norm_w[0] * out_A[0] + x1 * norm_w[1] * out_A[1]
                 + x2 * norm_w[2] * out_A[2] + x3 * norm_w[3] * out_A[3]
                 + x4 * norm_w[4] * out_A[4]) * r;
    }
    __syncthreads();

    if (tid < T) {
        const int t = tid;
        float q0 = QS[t][0], q1 = QS[t][1], q2 = QS[t][2], q3 = QS[t][3], q4 = QS[t][4];
        float mx = -1e30f;
        for (int s2 = 0; s2 < T; ++s2) {
            if (s2 <= t) {
                float d = (q0 * KS[s2][0] + q1 * KS[s2][1] + q2 * KS[s2][2]
                         + q3 * KS[s2][3] + q4 * KS[s2][4]) * 0.44721359549995793928f;
                ATTT[s2][t] = d;
                mx = fmaxf(mx, d);
            } else {
                ATTT[s2][t] = 0.f;   // zero-pad upper triangle -> uniform 34-iter dot later
            }
        }
        float sum = 0.f;
        for (int s2 = 0; s2 <= t; ++s2) {
            float e = expf(ATTT[s2][t] - mx);
            ATTT[s2][t] = e;
            sum += e;
        }
        float inv = 1.f / sum;
        for (int s2 = 0; s2 <= t; ++s2) ATTT[s2][t] *= inv;
    }

    // small weights -> (scalar) registers, uniform loads
    float nw[5], oB[5], w1[2][5], w2b[5][2], hw[2][5];
    #pragma unroll
    for (int d = 0; d < 5; ++d) { nw[d] = norm_w[d]; oB[d] = out_B[d]; }
    #pragma unroll
    for (int j = 0; j < 2; ++j) {
        #pragma unroll
        for (int d = 0; d < 5; ++d) { w1[j][d] = fc1_w[j*5+d]; hw[j][d] = head_w[j*5+d]; }
    }
    #pragma unroll
    for (int d = 0; d < 5; ++d) { w2b[d][0] = fc2_w[2*d]; w2b[d][1] = fc2_w[2*d+1]; }
    __syncthreads();

    // ================= grid-stride over item groups =================
    for (int grp = blockIdx.x; grp < NGROUPS; grp += NBLK) {
        const int gitem0 = grp * NT;                 // first (b,t) item of group
        const int b0 = gitem0 / T;
        const int bLast = (gitem0 + NT - 1) / T;
        const int nstage = (bLast - b0 + 1) * T;     // <= 306

        // stage tokens + per-row g for the covered rows (coalesced idx read)
        for (int i = tid; i < nstage; i += NT) {
            int tok = idx[b0 * T + i];
            int s2 = i % T;
            tokb[i] = (unsigned char)tok;
            gb[0][i] = G[tok][s2];                   // gb is [MAXROWS][T] flat
        }
        __syncthreads();

        // ---- one (b,t) item per thread ----
        const int item = gitem0 + tid;
        const int b = item / T;
        const int t = item - b * T;
        const int r = b - b0;

        float acc = 0.f;
        #pragma unroll
        for (int s2 = 0; s2 < T; ++s2)
            acc = fmaf(ATTT[s2][t], gb[r][s2], acc);

        int tok = tokb[r * T + t];
        float x0 = TE[tok][0] + acc * oB[0];
        float x1 = TE[tok][1] + acc * oB[1];
        float x2 = POS[t][0] + acc * oB[2];
        float x3 = POS[t][1] + acc * oB[3];
        float x4 = POS[t][2] + acc * oB[4];

        // FFN (pre-norm)
        float ms = (x0*x0 + x1*x1 + x2*x2 + x3*x3 + x4*x4) * 0.2f;
        float rr = rsqrtf(ms + 1e-5f);
        float h0 = x0*rr*nw[0], h1 = x1*rr*nw[1], h2 = x2*rr*nw[2], h3 = x3*rr*nw[3], h4 = x4*rr*nw[4];
        float f0 = fmaxf(0.f, h0*w1[0][0] + h1*w1[0][1] + h2*w1[0][2] + h3*w1[0][3] + h4*w1[0][4]);
        float f1 = fmaxf(0.f, h0*w1[1][0] + h1*w1[1][1] + h2*w1[1][2] + h3*w1[1][3] + h4*w1[1][4]);
        x0 += f0*w2b[0][0] + f1*w2b[0][1];
        x1 += f0*w2b[1][0] + f1*w2b[1][1];
        x2 += f0*w2b[2][0] + f1*w2b[2][1];
        x3 += f0*w2b[3][0] + f1*w2b[3][1];
        x4 += f0*w2b[4][0] + f1*w2b[4][1];

        // head (pre-norm)
        ms = (x0*x0 + x1*x1 + x2*x2 + x3*x3 + x4*x4) * 0.2f;
        rr = rsqrtf(ms + 1e-5f);
        h0 = x0*rr*nw[0]; h1 = x1*rr*nw[1]; h2 = x2*rr*nw[2]; h3 = x3*rr*nw[3]; h4 = x4*rr*nw[4];
        float p0 = h0*hw[0][0] + h1*hw[0][1] + h2*hw[0][2] + h3*hw[0][3] + h4*hw[0][4];
        float p1 = h0*hw[1][0] + h1*hw[1][1] + h2*hw[1][2] + h3*hw[1][3] + h4*hw[1][4];

        // 14 logits -> LDS staging (TE broadcast reads)
        #pragma unroll
        for (int v = 0; v < V; ++v)
            stagef[tid * V + v] = p0 * TE[v][0] + p1 * TE[v][1];
        __syncthreads();

        // ---- coalesced float4 block write: 14336 B contiguous ----
        {
            float4* op = reinterpret_cast<float4*>(out + (size_t)gitem0 * V);
            for (int i = tid; i < NT * V / 4; i += NT)   // 896 float4
                op[i] = stage4[i];
        }
        __syncthreads();   // protect stage/gb/tokb reuse next group
    }
}

extern "C" void kernel_launch(void* const* d_in, const int* in_sizes, int n_in,
                              void* d_out, int out_size, void* d_ws, size_t ws_size,
                              hipStream_t stream) {
    const int*   idx        = (const int*)  d_in[0];
    const float* tok_A      = (const float*)d_in[1];
    const float* tok_start  = (const float*)d_in[2];
    const float* tok_stride = (const float*)d_in[3];
    const float* sp_amp     = (const float*)d_in[4];
    const float* sp_phase   = (const float*)d_in[5];
    const float* sp_slope   = (const float*)d_in[6];
    const float* sp_offset  = (const float*)d_in[7];
    const float* norm_w     = (const float*)d_in[8];
    const float* q_w        = (const float*)d_in[9];
    const float* q_phase    = (const float*)d_in[10];
    const float* out_A      = (const float*)d_in[11];
    const float* out_B      = (const float*)d_in[12];
    const float* fc1_w      = (const float*)d_in[13];
    const float* fc2_w      = (const float*)d_in[14];
    const float* head_w     = (const float*)d_in[15];
    float* out = (float*)d_out;

    micro_fwd<<<NBLK, NT, 0, stream>>>(idx, tok_A, tok_start, tok_stride,
                                       sp_amp, sp_phase, sp_slope, sp_offset,
                                       norm_w, q_w, q_phase, out_A, out_B,
                                       fc1_w, fc2_w, head_w, out);
}

// Round 3
// 40.953 us; speedup vs baseline: 1.5556x; 1.1696x over previous
//
#include <hip/hip_runtime.h>
#include <math.h>

#define T 34
#define V 14
#define NT 256
#define NBLK 2176
#define NWAVES 8704            // NBLK * 4 waves
#define NTILES 34816           // 65536*34/64
#define LIM (65536 * 34)

// d_ws float layout:
//   [0 .. 1190)      A_pad[34][35]  softmaxed causal attn, row t = attn[t][s], 0 for s>t
//   [1190 .. 1680)   G_pad[14][35]  g(v,s) = rmsnorm(x(v,s)) . out_A
//   [1680 .. 1708)   TE[14][2]
//   [1708 .. 1810)   POS[34][3]

__global__ void setup_k(const float* __restrict__ tokA_p, const float* __restrict__ tokStart_p,
                        const float* __restrict__ tokStride_p, const float* __restrict__ spAmp_p,
                        const float* __restrict__ spPhase_p, const float* __restrict__ spSlope_p,
                        const float* __restrict__ spOffset_p, const float* __restrict__ norm_w,
                        const float* __restrict__ q_w, const float* __restrict__ q_phase,
                        const float* __restrict__ out_A, float* __restrict__ ws)
{
    __shared__ float sPOS[T][3];
    __shared__ float sK[T][5];
    __shared__ float sQ[T][5];
    __shared__ float sTE[V][2];
    __shared__ float sA[T][35];

    const int tid = threadIdx.x;   // 64 threads, 1 block

    if (tid < V) {
        float ang = tokStart_p[0] + (float)tid * tokStride_p[0];
        float c = tokA_p[0] * cosf(ang), s = tokA_p[0] * sinf(ang);
        sTE[tid][0] = c; sTE[tid][1] = s;
        ws[1680 + 2 * tid] = c; ws[1681 + 2 * tid] = s;
    }
    if (tid < T) {
        float th = (float)tid * 0.62831853071795864769f + spPhase_p[0];
        float p0 = spAmp_p[0] * cosf(th), p1 = spAmp_p[0] * sinf(th);
        float p2 = spSlope_p[0] * (float)tid + spOffset_p[0];
        sPOS[tid][0] = p0; sPOS[tid][1] = p1; sPOS[tid][2] = p2;
        ws[1708 + 3 * tid] = p0; ws[1709 + 3 * tid] = p1; ws[1710 + 3 * tid] = p2;
        float kk[5];
        #pragma unroll
        for (int i = 0; i < 5; ++i)
            kk[i] = p0 * q_w[3 * i] + p1 * q_w[3 * i + 1] + p2 * q_w[3 * i + 2];
        float cc = cosf(q_phase[0]), ss = sinf(q_phase[0]);
        #pragma unroll
        for (int i = 0; i < 5; ++i) sK[tid][i] = kk[i];
        sQ[tid][0] = cc * kk[0] - ss * kk[1];
        sQ[tid][1] = ss * kk[0] + cc * kk[1];
        sQ[tid][2] = kk[2]; sQ[tid][3] = kk[3]; sQ[tid][4] = kk[4];
    }
    __syncthreads();

    if (tid < T) {
        const int t = tid;
        float mx = -1e30f;
        for (int s = 0; s <= t; ++s) {
            float d = (sQ[t][0] * sK[s][0] + sQ[t][1] * sK[s][1] + sQ[t][2] * sK[s][2]
                     + sQ[t][3] * sK[s][3] + sQ[t][4] * sK[s][4]) * 0.44721359549995793928f;
            sA[t][s] = d;
            mx = fmaxf(mx, d);
        }
        float sum = 0.f;
        for (int s = 0; s <= t; ++s) { float e = expf(sA[t][s] - mx); sA[t][s] = e; sum += e; }
        float inv = 1.f / sum;
        for (int s = 0; s < 35; ++s) ws[t * 35 + s] = (s <= t) ? sA[t][s] * inv : 0.f;
    }
    for (int e = tid; e < 490; e += 64) {
        int v = e / 35, s = e - v * 35;
        float g = 0.f;
        if (s < T) {
            float x0 = sTE[v][0], x1 = sTE[v][1];
            float x2 = sPOS[s][0], x3 = sPOS[s][1], x4 = sPOS[s][2];
            float ms = (x0*x0 + x1*x1 + x2*x2 + x3*x3 + x4*x4) * 0.2f;
            float r = rsqrtf(ms + 1e-5f);
            g = (x0 * norm_w[0] * out_A[0] + x1 * norm_w[1] * out_A[1]
               + x2 * norm_w[2] * out_A[2] + x3 * norm_w[3] * out_A[3]
               + x4 * norm_w[4] * out_A[4]) * r;
        }
        ws[1190 + e] = g;
    }
}

__global__ __launch_bounds__(NT, 4) void micro_main(
    const int* __restrict__ idx, const float* __restrict__ ws, float* __restrict__ out,
    const float* __restrict__ norm_w, const float* __restrict__ out_B,
    const float* __restrict__ fc1_w, const float* __restrict__ fc2_w,
    const float* __restrict__ head_w)
{
    __shared__ float G_lds[V * 35];      // 1960 B
    __shared__ float TE_lds[V * 2];      // 112 B
    __shared__ float gbW[4][104];        // per-warp staged g
    __shared__ int   tokW[4][104];       // per-warp staged tokens
    __shared__ float stageAll[4 * 896];  // per-warp logit staging; aliased as A_pad at setup

    const int tid = threadIdx.x;
    const int w = tid >> 6, lane = tid & 63;
    const int wid = blockIdx.x * 4 + w;

    // ---- one-time table load (only 2 barriers in the whole kernel) ----
    for (int i = tid; i < 490; i += NT) G_lds[i] = ws[1190 + i];
    if (tid < 28) TE_lds[tid] = ws[1680 + tid];
    for (int i = tid; i < 1190; i += NT) stageAll[i] = ws[i];   // A_pad staged here
    __syncthreads();

    const int t = (wid * 64 + lane) % T;   // invariant across this wave's 4 tiles
    float A[T];
    #pragma unroll
    for (int s = 0; s < T; ++s) A[s] = stageAll[t * 35 + s];
    const float ps0 = ws[1708 + 3 * t], ps1 = ws[1709 + 3 * t], ps2 = ws[1710 + 3 * t];
    __syncthreads();   // A reads complete; stageAll now reusable as logit stage

    // uniform weights (literal-indexed -> scalar loads / SGPRs)
    const float nw0 = norm_w[0], nw1 = norm_w[1], nw2 = norm_w[2], nw3 = norm_w[3], nw4 = norm_w[4];
    const float oB0 = out_B[0], oB1 = out_B[1], oB2 = out_B[2], oB3 = out_B[3], oB4 = out_B[4];
    float w1[2][5], hw[2][5], w20[5], w21[5];
    #pragma unroll
    for (int j = 0; j < 2; ++j)
        #pragma unroll
        for (int d = 0; d < 5; ++d) { w1[j][d] = fc1_w[j*5+d]; hw[j][d] = head_w[j*5+d]; }
    #pragma unroll
    for (int d = 0; d < 5; ++d) { w20[d] = fc2_w[2*d]; w21[d] = fc2_w[2*d+1]; }
    float te0[V], te1[V];
    #pragma unroll
    for (int v = 0; v < V; ++v) { te0[v] = ws[1680 + 2*v]; te1[v] = ws[1681 + 2*v]; }

    // per-lane invariants for the 102-token staging
    const int s_a = (lane < T) ? lane : lane - T;
    const int i2 = lane + 64;
    const int s_b = (i2 < 68) ? i2 - 34 : i2 - 68;
    const bool act2 = (i2 < 102);

    float* gb = gbW[w];
    int*   tk = tokW[w];
    float* stg = stageAll + w * 896;
    float2* stg2 = reinterpret_cast<float2*>(stg);
    const float4* st4 = reinterpret_cast<const float4*>(stg);

    int tile = wid;
    int b0 = (tile * 64) / T;
    int tk0 = idx[b0 * T + lane];                       // always in range
    int tk1 = idx[min(b0 * T + lane + 64, LIM - 1)];    // clamp (value unused when OOB)

    for (int k = 0; k < 4; ++k) {
        // ---- warp-local gb/tok staging ----
        gb[lane] = G_lds[tk0 * 35 + s_a];
        tk[lane] = tk0;
        if (act2) { gb[i2] = G_lds[tk1 * 35 + s_b]; tk[i2] = tk1; }

        const int item = tile * 64 + lane;
        const int b = item / T;
        const int rbase = (b - b0) * T;

        // ---- prefetch next tile's tokens (hidden under this tile's compute) ----
        const int tile_n = tile + NWAVES;
        if (k < 3) {
            int b0n = (tile_n * 64) / T;
            tk0 = idx[b0n * T + lane];
            tk1 = idx[min(b0n * T + lane + 64, LIM - 1)];
            b0 = b0n;
        }

        asm volatile("s_waitcnt lgkmcnt(0)" ::: "memory");   // gb/tok visible (same wave)

        // ---- attention dot: A-column (regs) . g-row (LDS, cf b64) ----
        float acc = 0.f;
        const float2* gbp = reinterpret_cast<const float2*>(gb + rbase);
        #pragma unroll
        for (int s = 0; s < 17; ++s) {
            float2 gg = gbp[s];
            acc = fmaf(A[2*s], gg.x, acc);
            acc = fmaf(A[2*s+1], gg.y, acc);
        }

        const int tok = tk[rbase + t];
        float2 te = *reinterpret_cast<const float2*>(&TE_lds[tok * 2]);
        float x0 = te.x + acc * oB0;
        float x1 = te.y + acc * oB1;
        float x2 = ps0 + acc * oB2;
        float x3 = ps1 + acc * oB3;
        float x4 = ps2 + acc * oB4;

        // FFN (pre-norm)
        float ms = (x0*x0 + x1*x1 + x2*x2 + x3*x3 + x4*x4) * 0.2f;
        float rr = rsqrtf(ms + 1e-5f);
        float h0 = x0*rr*nw0, h1 = x1*rr*nw1, h2 = x2*rr*nw2, h3 = x3*rr*nw3, h4 = x4*rr*nw4;
        float f0 = fmaxf(0.f, h0*w1[0][0] + h1*w1[0][1] + h2*w1[0][2] + h3*w1[0][3] + h4*w1[0][4]);
        float f1 = fmaxf(0.f, h0*w1[1][0] + h1*w1[1][1] + h2*w1[1][2] + h3*w1[1][3] + h4*w1[1][4]);
        x0 += f0*w20[0] + f1*w21[0];
        x1 += f0*w20[1] + f1*w21[1];
        x2 += f0*w20[2] + f1*w21[2];
        x3 += f0*w20[3] + f1*w21[3];
        x4 += f0*w20[4] + f1*w21[4];

        // head (pre-norm)
        ms = (x0*x0 + x1*x1 + x2*x2 + x3*x3 + x4*x4) * 0.2f;
        rr = rsqrtf(ms + 1e-5f);
        h0 = x0*rr*nw0; h1 = x1*rr*nw1; h2 = x2*rr*nw2; h3 = x3*rr*nw3; h4 = x4*rr*nw4;
        float p0 = h0*hw[0][0] + h1*hw[0][1] + h2*hw[0][2] + h3*hw[0][3] + h4*hw[0][4];
        float p1 = h0*hw[1][0] + h1*hw[1][1] + h2*hw[1][2] + h3*hw[1][3] + h4*hw[1][4];

        // ---- logits -> warp-local stage (7 x ds_write_b64) ----
        #pragma unroll
        for (int j = 0; j < 7; ++j) {
            float2 o2;
            o2.x = p0 * te0[2*j]   + p1 * te1[2*j];
            o2.y = p0 * te0[2*j+1] + p1 * te1[2*j+1];
            stg2[lane * 7 + j] = o2;
        }
        asm volatile("s_waitcnt lgkmcnt(0)" ::: "memory");   // stage visible (same wave)

        // ---- coalesced copyout: 3584 B contiguous per tile, fire-and-forget ----
        float4* outp = reinterpret_cast<float4*>(out) + (size_t)tile * 224;
        outp[lane]       = st4[lane];
        outp[lane + 64]  = st4[lane + 64];
        outp[lane + 128] = st4[lane + 128];
        if (lane < 32) outp[lane + 192] = st4[lane + 192];

        tile = tile_n;
    }
}

extern "C" void kernel_launch(void* const* d_in, const int* in_sizes, int n_in,
                              void* d_out, int out_size, void* d_ws, size_t ws_size,
                              hipStream_t stream) {
    const int*   idx        = (const int*)  d_in[0];
    const float* tok_A      = (const float*)d_in[1];
    const float* tok_start  = (const float*)d_in[2];
    const float* tok_stride = (const float*)d_in[3];
    const float* sp_amp     = (const float*)d_in[4];
    const float* sp_phase   = (const float*)d_in[5];
    const float* sp_slope   = (const float*)d_in[6];
    const float* sp_offset  = (const float*)d_in[7];
    const float* norm_w     = (const float*)d_in[8];
    const float* q_w        = (const float*)d_in[9];
    const float* q_phase    = (const float*)d_in[10];
    const float* out_A      = (const float*)d_in[11];
    const float* out_B      = (const float*)d_in[12];
    const float* fc1_w      = (const float*)d_in[13];
    const float* fc2_w      = (const float*)d_in[14];
    const float* head_w     = (const float*)d_in[15];
    float* out = (float*)d_out;
    float* ws  = (float*)d_ws;

    setup_k<<<1, 64, 0, stream>>>(tok_A, tok_start, tok_stride, sp_amp, sp_phase,
                                  sp_slope, sp_offset, norm_w, q_w, q_phase, out_A, ws);
    micro_main<<<NBLK, NT, 0, stream>>>(idx, ws, out, norm_w, out_B, fc1_w, fc2_w, head_w);
}

// Round 4
// 40.648 us; speedup vs baseline: 1.5673x; 1.0075x over previous
//
#include <hip/hip_runtime.h>
#include <math.h>

#define T 34
#define V 14
#define NT 256
#define NBLK 2176
#define NWAVES 8704            // NBLK * 4 waves
#define KTILES 4               // tiles per wave; NWAVES*KTILES*64 = 65536*34
#define LIM (65536 * 34)

// d_ws float layout:
//   [0 .. 1190)      A_pad[34][35]  softmaxed causal attn, row t = attn[t][s], 0 for s>t
//   [1190 .. 1680)   G_pad[14][35]  g(v,s) = rmsnorm(x(v,s)) . out_A
//   [1680 .. 1708)   TE[14][2]
//   [1708 .. 1810)   POS[34][3]

__global__ void setup_k(const float* __restrict__ tokA_p, const float* __restrict__ tokStart_p,
                        const float* __restrict__ tokStride_p, const float* __restrict__ spAmp_p,
                        const float* __restrict__ spPhase_p, const float* __restrict__ spSlope_p,
                        const float* __restrict__ spOffset_p, const float* __restrict__ norm_w,
                        const float* __restrict__ q_w, const float* __restrict__ q_phase,
                        const float* __restrict__ out_A, float* __restrict__ ws)
{
    __shared__ float sPOS[T][3];
    __shared__ float sK[T][5];
    __shared__ float sQ[T][5];
    __shared__ float sTE[V][2];
    __shared__ float sA[T][35];

    const int tid = threadIdx.x;   // 64 threads, 1 block

    if (tid < V) {
        float ang = tokStart_p[0] + (float)tid * tokStride_p[0];
        float c = tokA_p[0] * cosf(ang), s = tokA_p[0] * sinf(ang);
        sTE[tid][0] = c; sTE[tid][1] = s;
        ws[1680 + 2 * tid] = c; ws[1681 + 2 * tid] = s;
    }
    if (tid < T) {
        float th = (float)tid * 0.62831853071795864769f + spPhase_p[0];
        float p0 = spAmp_p[0] * cosf(th), p1 = spAmp_p[0] * sinf(th);
        float p2 = spSlope_p[0] * (float)tid + spOffset_p[0];
        sPOS[tid][0] = p0; sPOS[tid][1] = p1; sPOS[tid][2] = p2;
        ws[1708 + 3 * tid] = p0; ws[1709 + 3 * tid] = p1; ws[1710 + 3 * tid] = p2;
        float kk[5];
        #pragma unroll
        for (int i = 0; i < 5; ++i)
            kk[i] = p0 * q_w[3 * i] + p1 * q_w[3 * i + 1] + p2 * q_w[3 * i + 2];
        float cc = cosf(q_phase[0]), ss = sinf(q_phase[0]);
        #pragma unroll
        for (int i = 0; i < 5; ++i) sK[tid][i] = kk[i];
        sQ[tid][0] = cc * kk[0] - ss * kk[1];
        sQ[tid][1] = ss * kk[0] + cc * kk[1];
        sQ[tid][2] = kk[2]; sQ[tid][3] = kk[3]; sQ[tid][4] = kk[4];
    }
    __syncthreads();

    if (tid < T) {
        const int t = tid;
        float mx = -1e30f;
        for (int s = 0; s <= t; ++s) {
            float d = (sQ[t][0] * sK[s][0] + sQ[t][1] * sK[s][1] + sQ[t][2] * sK[s][2]
                     + sQ[t][3] * sK[s][3] + sQ[t][4] * sK[s][4]) * 0.44721359549995793928f;
            sA[t][s] = d;
            mx = fmaxf(mx, d);
        }
        float sum = 0.f;
        for (int s = 0; s <= t; ++s) { float e = expf(sA[t][s] - mx); sA[t][s] = e; sum += e; }
        float inv = 1.f / sum;
        for (int s = 0; s < 35; ++s) ws[t * 35 + s] = (s <= t) ? sA[t][s] * inv : 0.f;
    }
    for (int e = tid; e < 490; e += 64) {
        int v = e / 35, s = e - v * 35;
        float g = 0.f;
        if (s < T) {
            float x0 = sTE[v][0], x1 = sTE[v][1];
            float x2 = sPOS[s][0], x3 = sPOS[s][1], x4 = sPOS[s][2];
            float ms = (x0*x0 + x1*x1 + x2*x2 + x3*x3 + x4*x4) * 0.2f;
            float r = rsqrtf(ms + 1e-5f);
            g = (x0 * norm_w[0] * out_A[0] + x1 * norm_w[1] * out_A[1]
               + x2 * norm_w[2] * out_A[2] + x3 * norm_w[3] * out_A[3]
               + x4 * norm_w[4] * out_A[4]) * r;
        }
        ws[1190 + e] = g;
    }
}

__global__ __launch_bounds__(NT, 4) void micro_main(
    const int* __restrict__ idx, const float* __restrict__ ws, float* __restrict__ out,
    const float* __restrict__ norm_w, const float* __restrict__ out_B,
    const float* __restrict__ fc1_w, const float* __restrict__ fc2_w,
    const float* __restrict__ head_w)
{
    __shared__ float G_lds[V * 35];      // 1960 B
    __shared__ float TE_lds[V * 2];      // 112 B
    __shared__ float gbW[4][104];        // per-warp staged g
    __shared__ float stageAll[4 * 896];  // per-warp logit staging; aliased as A_pad at setup

    const int tid = threadIdx.x;
    const int w = tid >> 6, lane = tid & 63;
    const int wid = blockIdx.x * 4 + w;

    // ---- one-time table load (only 2 barriers in the whole kernel) ----
    for (int i = tid; i < 490; i += NT) G_lds[i] = ws[1190 + i];
    if (tid < 28) TE_lds[tid] = ws[1680 + tid];
    for (int i = tid; i < 1190; i += NT) stageAll[i] = ws[i];   // A_pad staged here
    __syncthreads();

    const int t = (wid * 64 + lane) % T;   // invariant across this wave's tiles
    float A[T];
    #pragma unroll
    for (int s = 0; s < T; ++s) A[s] = stageAll[t * 35 + s];
    const float ps0 = ws[1708 + 3 * t], ps1 = ws[1709 + 3 * t], ps2 = ws[1710 + 3 * t];
    __syncthreads();   // A reads complete; stageAll now reusable as logit stage

    // uniform weights (literal-indexed -> scalar loads / SGPRs)
    const float nw0 = norm_w[0], nw1 = norm_w[1], nw2 = norm_w[2], nw3 = norm_w[3], nw4 = norm_w[4];
    const float oB0 = out_B[0], oB1 = out_B[1], oB2 = out_B[2], oB3 = out_B[3], oB4 = out_B[4];
    float w1[2][5], hw[2][5], w20[5], w21[5];
    #pragma unroll
    for (int j = 0; j < 2; ++j)
        #pragma unroll
        for (int d = 0; d < 5; ++d) { w1[j][d] = fc1_w[j*5+d]; hw[j][d] = head_w[j*5+d]; }
    #pragma unroll
    for (int d = 0; d < 5; ++d) { w20[d] = fc2_w[2*d]; w21[d] = fc2_w[2*d+1]; }
    float te0[V], te1[V];
    #pragma unroll
    for (int v = 0; v < V; ++v) { te0[v] = ws[1680 + 2*v]; te1[v] = ws[1681 + 2*v]; }

    // per-lane invariants for the 102-value g staging
    const int s_a = (lane < T) ? lane : lane - T;
    const int i2 = lane + 64;
    const int s_b = (i2 < 68) ? i2 - 34 : i2 - 68;
    const bool act2 = (i2 < 102);

    float* gb = gbW[w];
    float* stg = stageAll + w * 896;
    float2* stg2 = reinterpret_cast<float2*>(stg);
    const float4* st4 = reinterpret_cast<const float4*>(stg);

    int tile = wid;
    int b0 = (tile * 64) / T;
    int tk0 = idx[b0 * T + lane];                       // always in range
    int tk1 = idx[min(b0 * T + lane + 64, LIM - 1)];    // clamp (value unused when OOB)
    int tko = idx[tile * 64 + lane];                    // this lane's own token

    #pragma unroll
    for (int k = 0; k < KTILES; ++k) {
        // ---- warp-local g staging (same-wave LDS ops are processed in order;
        //      compiler inserts the minimal counted lgkmcnt before any use) ----
        gb[lane] = G_lds[tk0 * 35 + s_a];
        if (act2) gb[i2] = G_lds[tk1 * 35 + s_b];

        const int item = tile * 64 + lane;
        const int b = item / T;
        const int rbase = (b - b0) * T;
        const int curtok = tko;
        const int tile_n = tile + NWAVES;

        // ---- prefetch next tile's tokens (hidden under this tile's compute) ----
        if (k < KTILES - 1) {
            int b0n = (tile_n * 64) / T;
            tk0 = idx[b0n * T + lane];
            tk1 = idx[min(b0n * T + lane + 64, LIM - 1)];
            tko = idx[tile_n * 64 + lane];
            b0 = b0n;
        }

        // ---- attention dot: A-column (regs) . g-row (LDS, broadcast-friendly) ----
        float acc = 0.f;
        const float2* gbp = reinterpret_cast<const float2*>(gb + rbase);
        #pragma unroll
        for (int s = 0; s < 17; ++s) {
            float2 gg = gbp[s];
            acc = fmaf(A[2*s], gg.x, acc);
            acc = fmaf(A[2*s+1], gg.y, acc);
        }

        float2 te = *reinterpret_cast<const float2*>(&TE_lds[curtok * 2]);
        float x0 = te.x + acc * oB0;
        float x1 = te.y + acc * oB1;
        float x2 = ps0 + acc * oB2;
        float x3 = ps1 + acc * oB3;
        float x4 = ps2 + acc * oB4;

        // FFN (pre-norm)
        float ms = (x0*x0 + x1*x1 + x2*x2 + x3*x3 + x4*x4) * 0.2f;
        float rr = rsqrtf(ms + 1e-5f);
        float h0 = x0*rr*nw0, h1 = x1*rr*nw1, h2 = x2*rr*nw2, h3 = x3*rr*nw3, h4 = x4*rr*nw4;
        float f0 = fmaxf(0.f, h0*w1[0][0] + h1*w1[0][1] + h2*w1[0][2] + h3*w1[0][3] + h4*w1[0][4]);
        float f1 = fmaxf(0.f, h0*w1[1][0] + h1*w1[1][1] + h2*w1[1][2] + h3*w1[1][3] + h4*w1[1][4]);
        x0 += f0*w20[0] + f1*w21[0];
        x1 += f0*w20[1] + f1*w21[1];
        x2 += f0*w20[2] + f1*w21[2];
        x3 += f0*w20[3] + f1*w21[3];
        x4 += f0*w20[4] + f1*w21[4];

        // head (pre-norm)
        ms = (x0*x0 + x1*x1 + x2*x2 + x3*x3 + x4*x4) * 0.2f;
        rr = rsqrtf(ms + 1e-5f);
        h0 = x0*rr*nw0; h1 = x1*rr*nw1; h2 = x2*rr*nw2; h3 = x3*rr*nw3; h4 = x4*rr*nw4;
        float p0 = h0*hw[0][0] + h1*hw[0][1] + h2*hw[0][2] + h3*hw[0][3] + h4*hw[0][4];
        float p1 = h0*hw[1][0] + h1*hw[1][1] + h2*hw[1][2] + h3*hw[1][3] + h4*hw[1][4];

        // ---- logits -> warp-local stage (7 x ds_write_b64) ----
        #pragma unroll
        for (int j = 0; j < 7; ++j) {
            float2 o2;
            o2.x = p0 * te0[2*j]   + p1 * te1[2*j];
            o2.y = p0 * te0[2*j+1] + p1 * te1[2*j+1];
            stg2[lane * 7 + j] = o2;
        }

        // ---- coalesced copyout: 3584 B contiguous per tile, fire-and-forget ----
        float4* outp = reinterpret_cast<float4*>(out) + (size_t)tile * 224;
        outp[lane]       = st4[lane];
        outp[lane + 64]  = st4[lane + 64];
        outp[lane + 128] = st4[lane + 128];
        if (lane < 32) outp[lane + 192] = st4[lane + 192];

        tile = tile_n;
    }
}

extern "C" void kernel_launch(void* const* d_in, const int* in_sizes, int n_in,
                              void* d_out, int out_size, void* d_ws, size_t ws_size,
                              hipStream_t stream) {
    const int*   idx        = (const int*)  d_in[0];
    const float* tok_A      = (const float*)d_in[1];
    const float* tok_start  = (const float*)d_in[2];
    const float* tok_stride = (const float*)d_in[3];
    const float* sp_amp     = (const float*)d_in[4];
    const float* sp_phase   = (const float*)d_in[5];
    const float* sp_slope   = (const float*)d_in[6];
    const float* sp_offset  = (const float*)d_in[7];
    const float* norm_w     = (const float*)d_in[8];
    const float* q_w        = (const float*)d_in[9];
    const float* q_phase    = (const float*)d_in[10];
    const float* out_A      = (const float*)d_in[11];
    const float* out_B      = (const float*)d_in[12];
    const float* fc1_w      = (const float*)d_in[13];
    const float* fc2_w      = (const float*)d_in[14];
    const float* head_w     = (const float*)d_in[15];
    float* out = (float*)d_out;
    float* ws  = (float*)d_ws;

    setup_k<<<1, 64, 0, stream>>>(tok_A, tok_start, tok_stride, sp_amp, sp_phase,
                                  sp_slope, sp_offset, norm_w, q_w, q_phase, out_A, ws);
    micro_main<<<NBLK, NT, 0, stream>>>(idx, ws, out, norm_w, out_B, fc1_w, fc2_w, head_w);
}